// Round 2
// baseline (254.954 us; speedup 1.0000x reference)
//
#include <hip/hip_runtime.h>

#define NT     111
#define LMAX   5
#define TAU    32
#define NBATCH 32
#define ROW    2304   // f32 elements per batch row of fs

struct Tup { int l, l1, l2, out_off, in1, in2; };
struct Meta { Tup t[NT]; int totch; };

constexpr int IN_OFF[LMAX + 1] = {0, 64, 256, 576, 1024, 1600};

constexpr Meta make_meta() {
  Meta m{};
  int n = 0, out = 0;
  for (int l = 0; l <= LMAX; ++l)
    for (int l1 = 0; l1 <= LMAX; ++l1)
      for (int l2 = 0; l2 <= LMAX; ++l2) {
        int df = l1 - l2; if (df < 0) df = -df;
        if (df <= l && l <= l1 + l2) {
          m.t[n].l = l; m.t[n].l1 = l1; m.t[n].l2 = l2;
          m.t[n].out_off = out;
          m.t[n].in1 = IN_OFF[l1]; m.t[n].in2 = IN_OFF[l2];
          out += TAU * TAU * (2 * l + 1);
          ++n;
        }
      }
  m.totch = out;
  return m;
}

constexpr Meta META  = make_meta();
constexpr int  TOTCH = META.totch;   // 789504 channel pairs per batch

__constant__ Meta d_META = make_meta();

constexpr double cfact(int n) { double r = 1.0; for (int i = 2; i <= n; ++i) r *= i; return r; }
__constant__ double d_FACT[17] = {
  cfact(0), cfact(1), cfact(2),  cfact(3),  cfact(4),  cfact(5),  cfact(6),  cfact(7),
  cfact(8), cfact(9), cfact(10), cfact(11), cfact(12), cfact(13), cfact(14), cfact(15), cfact(16)
};

// Condon-Shortley CG coefficient <j1 m1 j2 m2 | j3 m3>, Racah formula, f64 (exact factorials).
__device__ double cg_coef_dev(int j1, int m1, int j2, int m2, int j3, int m3) {
  double pref = sqrt((2.0 * j3 + 1.0) * d_FACT[j3 + j1 - j2] * d_FACT[j3 - j1 + j2] *
                     d_FACT[j1 + j2 - j3] / d_FACT[j1 + j2 + j3 + 1]);
  pref *= sqrt(d_FACT[j3 + m3] * d_FACT[j3 - m3] * d_FACT[j1 - m1] * d_FACT[j1 + m1] *
               d_FACT[j2 - m2] * d_FACT[j2 + m2]);
  double s = 0.0;
  const int kmax = j1 + j2 - j3;
  for (int k = 0; k <= kmax; ++k) {
    const int a3 = j1 - m1 - k, a4 = j2 + m2 - k, a5 = j3 - j2 + m1 + k, a6 = j3 - j1 - m2 + k;
    if (a3 < 0 || a4 < 0 || a5 < 0 || a6 < 0) continue;
    const double den = d_FACT[k] * d_FACT[kmax - k] * d_FACT[a3] * d_FACT[a4] * d_FACT[a5] * d_FACT[a6];
    s += ((k & 1) ? -1.0 : 1.0) / den;
  }
  return pref * s;
}

// One block per (tuple, batch). Self-contained: computes the tuple's CG block
// into LDS (no d_ws), stages both input fragments in LDS, then streams
// coalesced float2 (re,im) outputs.
__global__ void __launch_bounds__(256)
cg_main(const float* __restrict__ fs, float2* __restrict__ out) {
  __shared__ float sa[11 * TAU * 2];   // parts[l1][b]: [t1][m1][re,im]
  __shared__ float sb[11 * TAU * 2];   // parts[l2][b]: [t2][m2][re,im]
  __shared__ float sc[11 * 121];       // CG block: [m][(m1+l1)*d2+(m2+l2)]

  const Tup T = d_META.t[blockIdx.x];
  const int b  = blockIdx.y;
  const int l  = T.l, l1 = T.l1, l2 = T.l2;
  const int d  = 2 * l + 1, d1 = 2 * l1 + 1, d2 = 2 * l2 + 1;
  const int K  = d1 * d2, ncg = d * K;

  // Phase 0: CG block -> LDS (f64 Racah, exact factorials <= 16!)
  for (int e = threadIdx.x; e < ncg; e += 256) {
    const int m = e / K, k = e - m * K;
    const int q = k / d2;
    const int m1 = q - l1, m2 = (k - q * d2) - l2, mm = m - l;
    double v = 0.0;
    if (m1 + m2 == mm) v = cg_coef_dev(l1, m1, l2, m2, l, mm);
    sc[e] = (float)v;
  }

  // Phase 1: input fragments -> LDS (f32 input!)
  const float* pa = fs + b * ROW + T.in1;
  for (int i = threadIdx.x; i < d1 * TAU * 2; i += 256) sa[i] = pa[i];
  const float* pb = fs + b * ROW + T.in2;
  for (int i = threadIdx.x; i < d2 * TAU * 2; i += 256) sb[i] = pb[i];
  __syncthreads();

  // Phase 2: each thread walks output positions o = tp*d + m with stride 256.
  const int n_out = TAU * TAU * d;
  float2* po = out + (size_t)b * TOTCH + T.out_off;

  int o  = threadIdx.x;
  int tp = o / d, m = o - tp * d;
  const int step_tp = 256 / d, step_m = 256 - step_tp * d;

  for (; o < n_out; o += 256) {
    const int t1 = tp >> 5, t2 = tp & 31;
    const int ms = m - l;
    int lo = -l1; if (ms - l2 > lo) lo = ms - l2;
    int hi =  l1; if (ms + l2 < hi) hi = ms + l2;

    const float* arow = sa + t1 * (d1 * 2);
    const float* brow = sb + t2 * (d2 * 2);
    const float* crow = sc + m * K;

    float re = 0.f, im = 0.f;
    for (int m1 = lo; m1 <= hi; ++m1) {
      const int i1 = m1 + l1, i2 = (ms - m1) + l2;
      const float c  = crow[i1 * d2 + i2];
      const float ar = arow[i1 * 2], ai = arow[i1 * 2 + 1];
      const float br = brow[i2 * 2], bi = brow[i2 * 2 + 1];
      re += c * (ar * br - ai * bi);
      im += c * (ar * bi + ai * br);
    }
    po[o] = make_float2(re, im);

    m += step_m; tp += step_tp;
    if (m >= d) { m -= d; ++tp; }
  }
}

extern "C" void kernel_launch(void* const* d_in, const int* in_sizes, int n_in,
                              void* d_out, int out_size, void* d_ws, size_t ws_size,
                              hipStream_t stream) {
  const float* fs = (const float*)d_in[0];   // f32 per the reference
  float2* out = (float2*)d_out;              // f32 (re,im) pairs per the reference
  (void)d_ws; (void)ws_size; (void)in_sizes; (void)n_in; (void)out_size;

  cg_main<<<dim3(NT, NBATCH), dim3(256), 0, stream>>>(fs, out);
}

// Round 3
// 240.099 us; speedup vs baseline: 1.0619x; 1.0619x over previous
//
#include <hip/hip_runtime.h>

#define NT     111
#define LMAX   5
#define TAU    32
#define NBATCH 32
#define ROW    2304   // f32 elements per batch row of fs

struct Tup { int l, l1, l2, out_off, in1, in2; };
struct Meta { Tup t[NT]; int totch; };

constexpr int IN_OFF[LMAX + 1] = {0, 64, 256, 576, 1024, 1600};

constexpr Meta make_meta() {
  Meta m{};
  int n = 0, out = 0;
  for (int l = 0; l <= LMAX; ++l)
    for (int l1 = 0; l1 <= LMAX; ++l1)
      for (int l2 = 0; l2 <= LMAX; ++l2) {
        int df = l1 - l2; if (df < 0) df = -df;
        if (df <= l && l <= l1 + l2) {
          m.t[n].l = l; m.t[n].l1 = l1; m.t[n].l2 = l2;
          m.t[n].out_off = out;
          m.t[n].in1 = IN_OFF[l1]; m.t[n].in2 = IN_OFF[l2];
          out += TAU * TAU * (2 * l + 1);
          ++n;
        }
      }
  m.totch = out;
  return m;
}

constexpr Meta META  = make_meta();
constexpr int  TOTCH = META.totch;   // 789504 complex pairs per batch

// ---------- compile-time CG coefficients ----------
constexpr double cfact(int n) { double r = 1.0; for (int i = 2; i <= n; ++i) r *= i; return r; }

constexpr double csqrt(double x) {
  if (x <= 0.0) return 0.0;
  double g = x;
  for (int i = 0; i < 100; ++i) g = 0.5 * (g + x / g);  // Newton, converges to f64 ulp
  return g;
}

// Condon-Shortley CG coefficient <j1 m1 j2 m2 | j3 m3>, Racah formula, f64 exact factorials.
constexpr double cg_coef_ct(int j1, int m1, int j2, int m2, int j3, int m3) {
  if (m1 + m2 != m3) return 0.0;
  double pref = csqrt((2.0 * j3 + 1.0) * cfact(j3 + j1 - j2) * cfact(j3 - j1 + j2) *
                      cfact(j1 + j2 - j3) / cfact(j1 + j2 + j3 + 1));
  pref *= csqrt(cfact(j3 + m3) * cfact(j3 - m3) * cfact(j1 - m1) * cfact(j1 + m1) *
                cfact(j2 - m2) * cfact(j2 + m2));
  double s = 0.0;
  const int kmax = j1 + j2 - j3;
  for (int k = 0; k <= kmax; ++k) {
    const int a3 = j1 - m1 - k, a4 = j2 + m2 - k, a5 = j3 - j2 + m1 + k, a6 = j3 - j1 - m2 + k;
    if (a3 < 0 || a4 < 0 || a5 < 0 || a6 < 0) continue;
    const double den = cfact(k) * cfact(kmax - k) * cfact(a3) * cfact(a4) * cfact(a5) * cfact(a6);
    s += ((k & 1) ? -1.0 : 1.0) / den;
  }
  return pref * s;
}

// Per-tuple constexpr table (separate variable per tuple keeps each constexpr
// evaluation ~100k steps, under clang's per-initializer limit).
template<int L, int L1, int L2>
struct CGTab {
  struct T { float v[2 * L + 1][2 * L1 + 1][2 * L2 + 1]; };
  static constexpr T gen() {
    T t{};
    for (int m = 0; m < 2 * L + 1; ++m)
      for (int i1 = 0; i1 < 2 * L1 + 1; ++i1)
        for (int i2 = 0; i2 < 2 * L2 + 1; ++i2)
          t.v[m][i1][i2] = (float)cg_coef_ct(L1, i1 - L1, L2, i2 - L2, L, m - L);
    return t;
  }
  static constexpr T tab = gen();
};

// ---------- fully-unrolled per-tuple contraction ----------
// Thread t owns (t1,t2) pairs tp = t + 256*j, j=0..3; t2 = t&31 is j-invariant
// (b-fragment registers reused across all 4 j's). All loops unroll to straight-
// line FMAs with CG values as immediate constants. No LDS, no divergence.
template<int L, int L1, int L2>
__device__ __forceinline__ void tuple_impl(const float* __restrict__ fa,
                                           const float* __restrict__ fb,
                                           float2* __restrict__ po) {
  constexpr int D = 2 * L + 1, D1 = 2 * L1 + 1, D2 = 2 * L2 + 1;
  const int tid = threadIdx.x;

  const int t2 = tid & 31;
  float br[D2], bi[D2];
  const float2* pb = (const float2*)fb + t2 * D2;
  #pragma unroll
  for (int i = 0; i < D2; ++i) { float2 v = pb[i]; br[i] = v.x; bi[i] = v.y; }

  #pragma unroll
  for (int j = 0; j < 4; ++j) {
    const int tp = tid + 256 * j;
    const int t1 = tp >> 5;

    float ar[D1], ai[D1];
    const float2* pa = (const float2*)fa + t1 * D1;
    #pragma unroll
    for (int i = 0; i < D1; ++i) { float2 v = pa[i]; ar[i] = v.x; ai[i] = v.y; }

    float2 res[D];
    #pragma unroll
    for (int m = 0; m < D; ++m) {
      float re = 0.f, im = 0.f;
      #pragma unroll
      for (int i1 = 0; i1 < D1; ++i1) {
        const int i2 = (m - L) - (i1 - L1) + L2;   // unroll-time constant
        if (i2 >= 0 && i2 < D2) {                   // folds after unrolling
          const float c = CGTab<L, L1, L2>::tab.v[m][i1][i2];  // immediate
          if (c != 0.f) {
            re += c * (ar[i1] * br[i2] - ai[i1] * bi[i2]);
            im += c * (ar[i1] * bi[i2] + ai[i1] * br[i2]);
          }
        }
      }
      res[m] = make_float2(re, im);
    }

    float2* o = po + tp * D;
    #pragma unroll
    for (int m = 0; m < D; ++m) o[m] = res[m];
  }
}

// ---------- compile-time dispatch over the 111 tuples ----------
template<int I>
__device__ __forceinline__ void dispatch(int idx, int b,
                                         const float* __restrict__ fs,
                                         float2* __restrict__ out) {
  if constexpr (I < NT) {
    if (idx == I) {
      constexpr Tup t = META.t[I];
      tuple_impl<t.l, t.l1, t.l2>(fs + b * ROW + t.in1,
                                  fs + b * ROW + t.in2,
                                  out + (size_t)b * TOTCH + t.out_off);
    } else {
      dispatch<I + 1>(idx, b, fs, out);
    }
  }
}

__global__ void __launch_bounds__(256)
cg_main(const float* __restrict__ fs, float2* __restrict__ out) {
  dispatch<0>(blockIdx.x, blockIdx.y, fs, out);
}

extern "C" void kernel_launch(void* const* d_in, const int* in_sizes, int n_in,
                              void* d_out, int out_size, void* d_ws, size_t ws_size,
                              hipStream_t stream) {
  const float* fs = (const float*)d_in[0];
  float2* out = (float2*)d_out;
  (void)d_ws; (void)ws_size; (void)in_sizes; (void)n_in; (void)out_size;

  cg_main<<<dim3(NT, NBATCH), dim3(256), 0, stream>>>(fs, out);
}